// Round 5
// baseline (4408.880 us; speedup 1.0000x reference)
//
#include <hip/hip_runtime.h>

typedef unsigned short u16;
typedef unsigned int   u32;
typedef unsigned long long u64;

#define B_    8
#define N_    8192
#define CIN   64
#define COUT  128
#define NS    2048
#define K_    32
#define LDSPAD 136   // 128 + 8 bf16: breaks bank conflicts on column stride

typedef __attribute__((ext_vector_type(8))) short short8;
typedef __attribute__((ext_vector_type(4))) float f32x4;

#define MFMA16(a,b,c) __builtin_amdgcn_mfma_f32_16x16x32_bf16(a,b,c,0,0,0)

__device__ __forceinline__ u16 f2bf(float f){
  u32 u = __float_as_uint(f);
  return (u16)((u + 0x7FFFu + ((u >> 16) & 1u)) >> 16);   // RNE, finite values only
}
__device__ __forceinline__ float bf2f(u16 h){ u32 u = ((u32)h) << 16; return __uint_as_float(u); }
__device__ __forceinline__ u32 pack2bf(float lo, float hi){ return (u32)f2bf(lo) | ((u32)f2bf(hi) << 16); }

// ---------------------------------------------------------------------------
// Weight f32 -> bf16 conversion (one-time prep into ws)
// ---------------------------------------------------------------------------
__global__ void wcvt_kernel(const float* __restrict__ s, u16* __restrict__ d, int n){
  int i = blockIdx.x * 256 + threadIdx.x;
  if (i < n) d[i] = f2bf(s[i]);
}

// ---------------------------------------------------------------------------
// BN constants: scale = g/sqrt(v+eps), bias = b - m*scale  (all f32 inputs)
// set order: 0=te, 1/2=pre0.bn1/bn2, 3/4=pre1.bn1/bn2, 5/6=pos0, 7/8=pos1
// ---------------------------------------------------------------------------
struct BnPtrs { const float* g[9]; const float* b[9]; const float* m[9]; const float* v[9]; };

__global__ void bn_pre_kernel(BnPtrs p, float* __restrict__ bns){
  int set = blockIdx.x, c = threadIdx.x;
  float sc = p.g[set][c] / sqrtf(p.v[set][c] + 1e-5f);
  bns[set*256 + c]       = sc;
  bns[set*256 + 128 + c] = p.b[set][c] - p.m[set][c] * sc;
}

// ---------------------------------------------------------------------------
// FPS: 1 block / batch, 512 threads, 16 pts/thread in registers.
// amdgpu_waves_per_eu(2,2) pins the allocator's occupancy TARGET at 2
// waves/EU (256-VGPR budget): r3/r4 showed __launch_bounds__(512,2) only
// sets the min — allocator targeted ~6 waves/EU and spilled px/py/pz
// (VGPR=48/76, FETCH_SIZE=415 MB of scratch re-reads both rounds).
// Reduction carries only (bv,bi); the wave-winner's owner thread
// (bi>>4, wave-uniform) extracts coords from its own registers via
// constant-index selects and writes the LDS record. Zero global loads
// in the step loop. Exact f32 (contract off), tie -> lowest index.
// ---------------------------------------------------------------------------
__global__ __attribute__((amdgpu_flat_work_group_size(512,512), amdgpu_waves_per_eu(2,2)))
void fps_kernel(const float* __restrict__ xyz, int* __restrict__ fps_idx){
  #pragma clang fp contract(off)
  const int b = blockIdx.x;
  const int t = threadIdx.x;
  const float* xb = xyz + (size_t)b * N_ * 3;
  float px[16], py[16], pz[16], dist[16];
  const int base = t * 16;
  #pragma unroll
  for (int j = 0; j < 16; ++j){
    px[j] = xb[(base + j)*3 + 0];
    py[j] = xb[(base + j)*3 + 1];
    pz[j] = xb[(base + j)*3 + 2];
    dist[j] = 1e10f;
  }
  __shared__ u64  kArr[2][8];
  __shared__ float xArr[2][8], yArr[2][8], zArr[2][8];
  if (t == 0) fps_idx[b*NS] = 0;
  float lx = xb[0], ly = xb[1], lz = xb[2];     // point 0 is the seed
  for (int s = 0; s < NS - 1; ++s){
    float bv = -1.0f; int bi = 0;
    #pragma unroll
    for (int j = 0; j < 16; ++j){
      float dx = px[j] - lx;
      float dy = py[j] - ly;
      float dz = pz[j] - lz;
      float t0 = dx*dx;
      float t1 = dy*dy;
      float t2 = dz*dz;
      float dd = (t0 + t1) + t2;                // same assoc as np.sum axis=-1
      float nd = fminf(dist[j], dd);
      dist[j] = nd;
      bool c = nd > bv;                         // strict > keeps earliest index
      bv = c ? nd : bv; bi = c ? base + j : bi;
    }
    #pragma unroll
    for (int off = 1; off < 64; off <<= 1){
      float ov = __shfl_xor(bv, off);
      int   oi = __shfl_xor(bi, off);
      bool c = (ov > bv) || (ov == bv && oi < bi);
      bv = c ? ov : bv; bi = c ? oi : bi;
    }
    const int sl = s & 1;
    // bi is wave-uniform; its owner thread (bi>>4) lives in this wave.
    if (t == (bi >> 4)){
      const int w = t >> 6;
      const int j = bi & 15;
      float sx = px[0], sy = py[0], sz = pz[0];
      #pragma unroll
      for (int k = 1; k < 16; ++k){
        bool e = (j == k);
        sx = e ? px[k] : sx; sy = e ? py[k] : sy; sz = e ? pz[k] : sz;
      }
      kArr[sl][w] = ((u64)__float_as_uint(bv) << 13) | (u64)(8191 - bi);
      xArr[sl][w] = sx; yArr[sl][w] = sy; zArr[sl][w] = sz;
    }
    __syncthreads();
    u64 win = kArr[sl][0]; int wsid = 0;
    #pragma unroll
    for (int wj = 1; wj < 8; ++wj){ u64 o = kArr[sl][wj]; if (o > win){ win = o; wsid = wj; } }
    lx = xArr[sl][wsid]; ly = yArr[sl][wsid]; lz = zArr[sl][wsid];
    if (t == 0) fps_idx[b*NS + s + 1] = 8191 - (int)(win & 0x1FFFull);
  }
}

// ---------------------------------------------------------------------------
// kNN: one wave per center, sorted 64-slot (d2,idx) lane-list, threshold =
// slot 31. Ballot pre-filter per 64-pt chunk, shfl_up sorted insertion.
// Exact f32 distances + lex (d2,idx) ties == stable top_k neighbor set.
// Also emits new_xyz (exact f32 gather).
// ---------------------------------------------------------------------------
__global__ __launch_bounds__(256) void knn_kernel(const float* __restrict__ xyz, const int* __restrict__ fps_idx,
                                                  int* __restrict__ knn, float* __restrict__ out_xyz){
  #pragma clang fp contract(off)
  const int wid = threadIdx.x >> 6, lane = threadIdx.x & 63;
  const int cg = blockIdx.x * 4 + wid;
  const int b = cg >> 11;
  const float* xb = xyz + (size_t)b * N_ * 3;
  const int ci = fps_idx[cg] & (N_ - 1);      // clamp: fault-proof
  const float cx = xb[ci*3], cy = xb[ci*3+1], cz = xb[ci*3+2];
  if (lane < 3) out_xyz[cg*3 + lane] = xb[ci*3 + lane];

  float rd = __uint_as_float(0x7F800000u); int ri = 0x7FFFFFFF;
  float r31d = rd; int r31i = ri;
  for (int c = 0; c < N_/64; ++c){
    const int pid = c*64 + lane;
    float dx = xb[pid*3]   - cx;
    float dy = xb[pid*3+1] - cy;
    float dz = xb[pid*3+2] - cz;
    float t0 = dx*dx, t1 = dy*dy, t2 = dz*dz;
    float d2 = (t0 + t1) + t2;
    u64 m = __ballot((d2 < r31d) || (d2 == r31d && pid < r31i));
    while (m){
      int l = __ffsll((long long)m) - 1; m &= m - 1;
      float v = __shfl(d2, l); int vi = c*64 + l;
      if (!((v < r31d) || (v == r31d && vi < r31i))) continue;  // re-check vs updated threshold
      bool lt = (rd < v) || (rd == v && ri < vi);
      int pos = __popcll(__ballot(lt));
      float prd = __shfl_up(rd, 1); int pri = __shfl_up(ri, 1);
      if (lane == pos){ rd = v; ri = vi; }
      else if (lane > pos){ rd = prd; ri = pri; }
      r31d = __shfl(rd, 31); r31i = __shfl(ri, 31);
    }
  }
  if (lane < K_) knn[(size_t)cg * K_ + lane] = ri;
}

// ---------------------------------------------------------------------------
// Conv stack helpers. Wave-private X tile [32 cols][136 ch] bf16 in LDS.
// MFMA 16x16x32 bf16: A[m=lane&15][k=q*8+j], B[k=q*8+j][n=lane&15],
// D col=lane&15, row=q*4+reg (m89-verified layouts). W is bf16 (pre-converted).
// ---------------------------------------------------------------------------
__device__ __forceinline__ void zero_acc(f32x4 acc[8][2]){
  #pragma unroll
  for (int mt = 0; mt < 8; ++mt)
    #pragma unroll
    for (int nt = 0; nt < 2; ++nt){
      acc[mt][nt][0] = 0.f; acc[mt][nt][1] = 0.f; acc[mt][nt][2] = 0.f; acc[mt][nt][3] = 0.f;
    }
}

__device__ __forceinline__ void conv_step(const u16* __restrict__ W, const u16* __restrict__ Xw,
                                          int q, int l15, f32x4 acc[8][2]){
  #pragma unroll
  for (int kk = 0; kk < 4; ++kk){
    short8 b0 = *(const short8*)(Xw + l15*LDSPAD + kk*32 + q*8);
    short8 b1 = *(const short8*)(Xw + (16 + l15)*LDSPAD + kk*32 + q*8);
    #pragma unroll
    for (int mt = 0; mt < 8; ++mt){
      short8 a = *(const short8*)(W + (size_t)(mt*16 + l15)*COUT + kk*32 + q*8);
      acc[mt][0] = MFMA16(a, b0, acc[mt][0]);
      acc[mt][1] = MFMA16(a, b1, acc[mt][1]);
    }
  }
}

// y1 = relu(bn1(W1@X)); out = relu(bn2(W2@y1) + resid). Leaves post-relu f32 in acc.
__device__ __forceinline__ void res_block(const u16* __restrict__ W1, const u16* __restrict__ W2,
    const float* __restrict__ bn1, const float* __restrict__ bn2,
    u16* __restrict__ Xw, int q, int l15, u32 resid[8][2][2], f32x4 acc[8][2], bool writeback){
  zero_acc(acc);
  conv_step(W1, Xw, q, l15, acc);
  #pragma unroll
  for (int mt = 0; mt < 8; ++mt){
    f32x4 sc = *(const f32x4*)(bn1 + mt*16 + q*4);
    f32x4 bi = *(const f32x4*)(bn1 + 128 + mt*16 + q*4);
    #pragma unroll
    for (int nt = 0; nt < 2; ++nt){
      float y0 = fmaxf(fmaf(acc[mt][nt][0], sc[0], bi[0]), 0.f);
      float y1 = fmaxf(fmaf(acc[mt][nt][1], sc[1], bi[1]), 0.f);
      float y2 = fmaxf(fmaf(acc[mt][nt][2], sc[2], bi[2]), 0.f);
      float y3 = fmaxf(fmaf(acc[mt][nt][3], sc[3], bi[3]), 0.f);
      *(uint2*)(Xw + (nt*16 + l15)*LDSPAD + mt*16 + q*4) = make_uint2(pack2bf(y0,y1), pack2bf(y2,y3));
    }
  }
  __syncthreads();
  zero_acc(acc);
  conv_step(W2, Xw, q, l15, acc);
  #pragma unroll
  for (int mt = 0; mt < 8; ++mt){
    f32x4 sc = *(const f32x4*)(bn2 + mt*16 + q*4);
    f32x4 bi = *(const f32x4*)(bn2 + 128 + mt*16 + q*4);
    #pragma unroll
    for (int nt = 0; nt < 2; ++nt){
      float r0 = bf2f((u16)(resid[mt][nt][0] & 0xFFFFu));
      float r1 = bf2f((u16)(resid[mt][nt][0] >> 16));
      float r2 = bf2f((u16)(resid[mt][nt][1] & 0xFFFFu));
      float r3 = bf2f((u16)(resid[mt][nt][1] >> 16));
      float y0 = fmaxf(fmaf(acc[mt][nt][0], sc[0], bi[0]) + r0, 0.f);
      float y1 = fmaxf(fmaf(acc[mt][nt][1], sc[1], bi[1]) + r1, 0.f);
      float y2 = fmaxf(fmaf(acc[mt][nt][2], sc[2], bi[2]) + r2, 0.f);
      float y3 = fmaxf(fmaf(acc[mt][nt][3], sc[3], bi[3]) + r3, 0.f);
      acc[mt][nt][0] = y0; acc[mt][nt][1] = y1; acc[mt][nt][2] = y2; acc[mt][nt][3] = y3;
      if (writeback){
        u32 p0 = pack2bf(y0,y1), p1 = pack2bf(y2,y3);
        resid[mt][nt][0] = p0; resid[mt][nt][1] = p1;
        *(uint2*)(Xw + (nt*16 + l15)*LDSPAD + mt*16 + q*4) = make_uint2(p0, p1);
      }
    }
  }
  if (writeback) __syncthreads();
}

// ---------------------------------------------------------------------------
// mid: gather(knn, f32 feat -> bf16) -> te conv -> 2 pre res-blocks -> maxpool.
// One wave per center; 4 waves/block. Output x_mid[g][128] bf16 (ws).
// ---------------------------------------------------------------------------
__global__ __launch_bounds__(256) void mid_kernel(const float* __restrict__ feat,
    const u16* __restrict__ te_w, const u16* __restrict__ pre_w1, const u16* __restrict__ pre_w2,
    const float* __restrict__ bns, const int* __restrict__ fps_idx, const int* __restrict__ knn,
    u16* __restrict__ x_mid){
  __shared__ __align__(16) u16 X[4][32*LDSPAD];
  __shared__ __align__(16) float scr[4][128];
  const int wid = threadIdx.x >> 6, lane = threadIdx.x & 63;
  const int q = lane >> 4, l15 = lane & 15;
  const int g = blockIdx.x*4 + wid;
  const int b = g >> 11;
  const float* fb = feat + (size_t)b * N_ * CIN;
  u16* Xw = X[wid];

  const int ctr = fps_idx[g] & (N_ - 1);
  const int* kg = knn + (size_t)g * K_;
  #pragma unroll
  for (int it = 0; it < 4; ++it){
    int lidx = it*64 + lane;
    int col = lidx >> 3, kq = lidx & 7;           // col<32, 8-ch chunk kq<8
    int nb = kg[col] & (N_ - 1);
    f32x4 a0 = *(const f32x4*)(fb + (size_t)nb*CIN + kq*8);
    f32x4 a1 = *(const f32x4*)(fb + (size_t)nb*CIN + kq*8 + 4);
    *(uint2*)(Xw + col*LDSPAD + kq*8)     = make_uint2(pack2bf(a0[0],a0[1]), pack2bf(a0[2],a0[3]));
    *(uint2*)(Xw + col*LDSPAD + kq*8 + 4) = make_uint2(pack2bf(a1[0],a1[1]), pack2bf(a1[2],a1[3]));
    f32x4 c0 = *(const f32x4*)(fb + (size_t)ctr*CIN + kq*8);
    f32x4 c1 = *(const f32x4*)(fb + (size_t)ctr*CIN + kq*8 + 4);
    *(uint2*)(Xw + col*LDSPAD + 64 + kq*8)     = make_uint2(pack2bf(c0[0],c0[1]), pack2bf(c0[2],c0[3]));
    *(uint2*)(Xw + col*LDSPAD + 64 + kq*8 + 4) = make_uint2(pack2bf(c1[0],c1[1]), pack2bf(c1[2],c1[3]));
  }
  __syncthreads();

  f32x4 acc[8][2];
  u32 resid[8][2][2];
  zero_acc(acc);
  conv_step(te_w, Xw, q, l15, acc);
  #pragma unroll
  for (int mt = 0; mt < 8; ++mt){
    f32x4 sc = *(const f32x4*)(bns + mt*16 + q*4);
    f32x4 bi = *(const f32x4*)(bns + 128 + mt*16 + q*4);
    #pragma unroll
    for (int nt = 0; nt < 2; ++nt){
      float y0 = fmaxf(fmaf(acc[mt][nt][0], sc[0], bi[0]), 0.f);
      float y1 = fmaxf(fmaf(acc[mt][nt][1], sc[1], bi[1]), 0.f);
      float y2 = fmaxf(fmaf(acc[mt][nt][2], sc[2], bi[2]), 0.f);
      float y3 = fmaxf(fmaf(acc[mt][nt][3], sc[3], bi[3]), 0.f);
      u32 p0 = pack2bf(y0,y1), p1 = pack2bf(y2,y3);
      resid[mt][nt][0] = p0; resid[mt][nt][1] = p1;
      *(uint2*)(Xw + (nt*16 + l15)*LDSPAD + mt*16 + q*4) = make_uint2(p0, p1);
    }
  }
  __syncthreads();

  res_block(pre_w1,             pre_w2,             bns + 256, bns + 512,  Xw, q, l15, resid, acc, true);
  res_block(pre_w1 + COUT*COUT, pre_w2 + COUT*COUT, bns + 768, bns + 1024, Xw, q, l15, resid, acc, false);

  // maxpool over 32 cols (nt pair + butterfly over low-4 lane bits)
  float mx[8][4];
  #pragma unroll
  for (int mt = 0; mt < 8; ++mt)
    #pragma unroll
    for (int r = 0; r < 4; ++r){
      float m0 = fmaxf(acc[mt][0][r], acc[mt][1][r]);
      #pragma unroll
      for (int off = 1; off < 16; off <<= 1) m0 = fmaxf(m0, __shfl_xor(m0, off));
      mx[mt][r] = m0;
    }
  if (l15 == 0){
    #pragma unroll
    for (int mt = 0; mt < 8; ++mt){
      f32x4 vv; vv[0] = mx[mt][0]; vv[1] = mx[mt][1]; vv[2] = mx[mt][2]; vv[3] = mx[mt][3];
      *(f32x4*)(scr[wid] + mt*16 + q*4) = vv;
    }
  }
  __syncthreads();
  float v0 = scr[wid][lane*2], v1 = scr[wid][lane*2 + 1];
  *(u32*)(x_mid + (size_t)g*COUT + lane*2) = pack2bf(v0, v1);
}

// ---------------------------------------------------------------------------
// pos: 2 res-blocks over (B,128,2048); one wave per 32 columns. f32 out.
// ---------------------------------------------------------------------------
__global__ __launch_bounds__(256) void pos_kernel(const u16* __restrict__ x_mid,
    const u16* __restrict__ pos_w1, const u16* __restrict__ pos_w2,
    const float* __restrict__ bns, float* __restrict__ out_x){
  __shared__ __align__(16) u16 X[4][32*LDSPAD];
  const int wid = threadIdx.x >> 6, lane = threadIdx.x & 63;
  const int q = lane >> 4, l15 = lane & 15;
  const int g = blockIdx.x*4 + wid;            // 0..511
  const int gc0 = g * 32;
  const int b = gc0 >> 11, s0 = gc0 & 2047;
  u16* Xw = X[wid];
  #pragma unroll
  for (int it = 0; it < 8; ++it){
    int lidx = it*64 + lane;
    int col = lidx >> 4, kq = lidx & 15;
    uint4 v = *(const uint4*)(x_mid + (size_t)(gc0 + col)*COUT + kq*8);
    *(uint4*)(Xw + col*LDSPAD + kq*8) = v;
  }
  __syncthreads();
  u32 resid[8][2][2];
  #pragma unroll
  for (int mt = 0; mt < 8; ++mt)
    #pragma unroll
    for (int nt = 0; nt < 2; ++nt){
      uint2 rr = *(const uint2*)(Xw + (nt*16 + l15)*LDSPAD + mt*16 + q*4);
      resid[mt][nt][0] = rr.x; resid[mt][nt][1] = rr.y;
    }
  f32x4 acc[8][2];
  res_block(pos_w1,             pos_w2,             bns + 1280, bns + 1536, Xw, q, l15, resid, acc, true);
  res_block(pos_w1 + COUT*COUT, pos_w2 + COUT*COUT, bns + 1792, bns + 2048, Xw, q, l15, resid, acc, false);
  #pragma unroll
  for (int mt = 0; mt < 8; ++mt)
    #pragma unroll
    for (int nt = 0; nt < 2; ++nt)
      #pragma unroll
      for (int r = 0; r < 4; ++r){
        int row = mt*16 + q*4 + r;
        int colx = s0 + nt*16 + l15;
        out_x[(size_t)(b*COUT + row)*NS + colx] = acc[mt][nt][r];
      }
}

// ---------------------------------------------------------------------------
extern "C" void kernel_launch(void* const* d_in, const int* in_sizes, int n_in,
                              void* d_out, int out_size, void* d_ws, size_t ws_size,
                              hipStream_t stream){
  (void)in_sizes; (void)n_in; (void)out_size; (void)ws_size;
  const float* xyz    = (const float*)d_in[0];
  const float* feat   = (const float*)d_in[1];

  // ws layout (16B aligned, ~6.4 MB total):
  char* ws = (char*)d_ws;
  float* bns     = (float*)ws;                          // 16 KiB (9.2 used)
  u16*   wbf     = (u16*)(ws + 16384);                  // 288 KiB bf16 weights
  int*   fps_idx = (int*)(ws + 16384 + 294912);         // 64 KiB
  int*   knn     = (int*)(ws + 16384 + 294912 + 65536); // 2 MiB
  u16*   x_mid   = (u16*)(ws + 16384 + 294912 + 65536 + 2097152); // 4 MiB
  float* out_xyz = (float*)d_out;                       // (8,2048,3) f32
  float* out_x   = (float*)d_out + B_*NS*3;             // (8,128,2048) f32

  // bf16 weight staging: te(16384) pre_w1(32768) pre_w2(32768) pos_w1(32768) pos_w2(32768)
  u16* te_w   = wbf;
  u16* pre_w1 = wbf + 16384;
  u16* pre_w2 = wbf + 49152;
  u16* pos_w1 = wbf + 81920;
  u16* pos_w2 = wbf + 114688;
  wcvt_kernel<<<64,  256, 0, stream>>>((const float*)d_in[2],  te_w,   16384);
  wcvt_kernel<<<128, 256, 0, stream>>>((const float*)d_in[7],  pre_w1, 32768);
  wcvt_kernel<<<128, 256, 0, stream>>>((const float*)d_in[8],  pre_w2, 32768);
  wcvt_kernel<<<128, 256, 0, stream>>>((const float*)d_in[17], pos_w1, 32768);
  wcvt_kernel<<<128, 256, 0, stream>>>((const float*)d_in[18], pos_w2, 32768);

  // dict order: te_g/b/m/v = 3..6 ; pre: w1,w2,g1,g2,b1,b2,m1,m2,v1,v2 = 7..16 ; pos = 17..26
  BnPtrs bp;
  const int gi[9] = {3, 9, 10, 9, 10, 19, 20, 19, 20};
  const int bbi[9]= {4, 11,12, 11,12, 21, 22, 21, 22};
  const int mi[9] = {5, 13,14, 13,14, 23, 24, 23, 24};
  const int vi[9] = {6, 15,16, 15,16, 25, 26, 25, 26};
  const int of[9] = {0, 0, 0, 128,128, 0, 0, 128,128};
  for (int k = 0; k < 9; ++k){
    bp.g[k] = (const float*)d_in[gi[k]]  + of[k];
    bp.b[k] = (const float*)d_in[bbi[k]] + of[k];
    bp.m[k] = (const float*)d_in[mi[k]]  + of[k];
    bp.v[k] = (const float*)d_in[vi[k]]  + of[k];
  }

  bn_pre_kernel<<<9, 128, 0, stream>>>(bp, bns);
  fps_kernel<<<B_, 512, 0, stream>>>(xyz, fps_idx);
  knn_kernel<<<(B_*NS)/4, 256, 0, stream>>>(xyz, fps_idx, knn, out_xyz);
  mid_kernel<<<(B_*NS)/4, 256, 0, stream>>>(feat, te_w, pre_w1, pre_w2, bns, fps_idx, knn, x_mid);
  pos_kernel<<<(B_*NS/K_)/4, 256, 0, stream>>>(x_mid, pos_w1, pos_w2, bns, out_x);
}

// Round 6
// 4399.149 us; speedup vs baseline: 1.0022x; 1.0022x over previous
//
#include <hip/hip_runtime.h>

typedef unsigned short u16;
typedef unsigned int   u32;
typedef unsigned long long u64;

#define B_    8
#define N_    8192
#define CIN   64
#define COUT  128
#define NS    2048
#define K_    32
#define LDSPAD 136   // 128 + 8 bf16: breaks bank conflicts on column stride

typedef __attribute__((ext_vector_type(8))) short short8;
typedef __attribute__((ext_vector_type(4))) float f32x4;

#define MFMA16(a,b,c) __builtin_amdgcn_mfma_f32_16x16x32_bf16(a,b,c,0,0,0)

__device__ __forceinline__ u16 f2bf(float f){
  u32 u = __float_as_uint(f);
  return (u16)((u + 0x7FFFu + ((u >> 16) & 1u)) >> 16);   // RNE, finite values only
}
__device__ __forceinline__ float bf2f(u16 h){ u32 u = ((u32)h) << 16; return __uint_as_float(u); }
__device__ __forceinline__ u32 pack2bf(float lo, float hi){ return (u32)f2bf(lo) | ((u32)f2bf(hi) << 16); }

// ---------------------------------------------------------------------------
// Weight f32 -> bf16 conversion (one-time prep into ws)
// ---------------------------------------------------------------------------
__global__ void wcvt_kernel(const float* __restrict__ s, u16* __restrict__ d, int n){
  int i = blockIdx.x * 256 + threadIdx.x;
  if (i < n) d[i] = f2bf(s[i]);
}

// ---------------------------------------------------------------------------
// BN constants: scale = g/sqrt(v+eps), bias = b - m*scale  (all f32 inputs)
// set order: 0=te, 1/2=pre0.bn1/bn2, 3/4=pre1.bn1/bn2, 5/6=pos0, 7/8=pos1
// ---------------------------------------------------------------------------
struct BnPtrs { const float* g[9]; const float* b[9]; const float* m[9]; const float* v[9]; };

__global__ void bn_pre_kernel(BnPtrs p, float* __restrict__ bns){
  int set = blockIdx.x, c = threadIdx.x;
  float sc = p.g[set][c] / sqrtf(p.v[set][c] + 1e-5f);
  bns[set*256 + c]       = sc;
  bns[set*256 + 128 + c] = p.b[set][c] - p.m[set][c] * sc;
}

// ---------------------------------------------------------------------------
// FPS: 1 block / batch, 512 threads, 16 pts/thread in registers.
// r3-r5 lesson: the compiler REMATERIALIZES px/py/pz (pure loads from
// readonly memory) instead of keeping them live -> ~48 re-issued global
// loads/thread/step (FETCH 415-421 MB, WRITE only 64 KB = no spill stores;
// occupancy attrs can't fix a remat decision). The empty inline-asm with
// "+v" constraints below makes each loaded value potentially-modified, so
// remat is illegal and the values are pinned in VGPRs. waves_per_eu(2,2)
// gives the 256-VGPR budget (~110 live needed -> no spill).
// Exact f32 (contract off) to bit-match np; argmax tie -> lowest index.
// ---------------------------------------------------------------------------
__global__ __attribute__((amdgpu_flat_work_group_size(512,512), amdgpu_waves_per_eu(2,2)))
void fps_kernel(const float* __restrict__ xyz, int* __restrict__ fps_idx){
  #pragma clang fp contract(off)
  const int b = blockIdx.x;
  const int t = threadIdx.x;
  const float* xb = xyz + (size_t)b * N_ * 3;
  float px[16], py[16], pz[16], dist[16];
  const int base = t * 16;
  #pragma unroll
  for (int j = 0; j < 16; ++j){
    px[j] = xb[(base + j)*3 + 0];
    py[j] = xb[(base + j)*3 + 1];
    pz[j] = xb[(base + j)*3 + 2];
    dist[j] = 1e10f;
  }
  #pragma unroll
  for (int j = 0; j < 16; ++j){
    asm volatile("" : "+v"(px[j]), "+v"(py[j]), "+v"(pz[j]));  // pin: defeat remat
  }
  __shared__ u64  kArr[2][8];
  __shared__ float xArr[2][8], yArr[2][8], zArr[2][8];
  if (t == 0) fps_idx[b*NS] = 0;
  float lx = xb[0], ly = xb[1], lz = xb[2];     // point 0 is the seed
  for (int s = 0; s < NS - 1; ++s){
    float bv = -1.0f; int bi = 0;
    #pragma unroll
    for (int j = 0; j < 16; ++j){
      float dx = px[j] - lx;
      float dy = py[j] - ly;
      float dz = pz[j] - lz;
      float t0 = dx*dx;
      float t1 = dy*dy;
      float t2 = dz*dz;
      float dd = (t0 + t1) + t2;                // same assoc as np.sum axis=-1
      float nd = fminf(dist[j], dd);
      dist[j] = nd;
      bool c = nd > bv;                         // strict > keeps earliest index
      bv = c ? nd : bv; bi = c ? base + j : bi;
    }
    #pragma unroll
    for (int off = 1; off < 64; off <<= 1){
      float ov = __shfl_xor(bv, off);
      int   oi = __shfl_xor(bi, off);
      bool c = (ov > bv) || (ov == bv && oi < bi);
      bv = c ? ov : bv; bi = c ? oi : bi;
    }
    const int sl = s & 1;
    // bi is wave-uniform; its owner thread (bi>>4) lives in this wave.
    if (t == (bi >> 4)){
      const int w = t >> 6;
      const int j = bi & 15;
      float sx = px[0], sy = py[0], sz = pz[0];
      #pragma unroll
      for (int k = 1; k < 16; ++k){
        bool e = (j == k);
        sx = e ? px[k] : sx; sy = e ? py[k] : sy; sz = e ? pz[k] : sz;
      }
      kArr[sl][w] = ((u64)__float_as_uint(bv) << 13) | (u64)(8191 - bi);
      xArr[sl][w] = sx; yArr[sl][w] = sy; zArr[sl][w] = sz;
    }
    __syncthreads();
    u64 win = kArr[sl][0]; int wsid = 0;
    #pragma unroll
    for (int wj = 1; wj < 8; ++wj){ u64 o = kArr[sl][wj]; if (o > win){ win = o; wsid = wj; } }
    lx = xArr[sl][wsid]; ly = yArr[sl][wsid]; lz = zArr[sl][wsid];
    if (t == 0) fps_idx[b*NS + s + 1] = 8191 - (int)(win & 0x1FFFull);
  }
}

// ---------------------------------------------------------------------------
// kNN: one wave per center, sorted 64-slot (d2,idx) lane-list, threshold =
// slot 31. Ballot pre-filter per 64-pt chunk, shfl_up sorted insertion.
// Exact f32 distances + lex (d2,idx) ties == stable top_k neighbor set.
// Also emits new_xyz (exact f32 gather).
// ---------------------------------------------------------------------------
__global__ __launch_bounds__(256) void knn_kernel(const float* __restrict__ xyz, const int* __restrict__ fps_idx,
                                                  int* __restrict__ knn, float* __restrict__ out_xyz){
  #pragma clang fp contract(off)
  const int wid = threadIdx.x >> 6, lane = threadIdx.x & 63;
  const int cg = blockIdx.x * 4 + wid;
  const int b = cg >> 11;
  const float* xb = xyz + (size_t)b * N_ * 3;
  const int ci = fps_idx[cg] & (N_ - 1);      // clamp: fault-proof
  const float cx = xb[ci*3], cy = xb[ci*3+1], cz = xb[ci*3+2];
  if (lane < 3) out_xyz[cg*3 + lane] = xb[ci*3 + lane];

  float rd = __uint_as_float(0x7F800000u); int ri = 0x7FFFFFFF;
  float r31d = rd; int r31i = ri;
  for (int c = 0; c < N_/64; ++c){
    const int pid = c*64 + lane;
    float dx = xb[pid*3]   - cx;
    float dy = xb[pid*3+1] - cy;
    float dz = xb[pid*3+2] - cz;
    float t0 = dx*dx, t1 = dy*dy, t2 = dz*dz;
    float d2 = (t0 + t1) + t2;
    u64 m = __ballot((d2 < r31d) || (d2 == r31d && pid < r31i));
    while (m){
      int l = __ffsll((long long)m) - 1; m &= m - 1;
      float v = __shfl(d2, l); int vi = c*64 + l;
      if (!((v < r31d) || (v == r31d && vi < r31i))) continue;  // re-check vs updated threshold
      bool lt = (rd < v) || (rd == v && ri < vi);
      int pos = __popcll(__ballot(lt));
      float prd = __shfl_up(rd, 1); int pri = __shfl_up(ri, 1);
      if (lane == pos){ rd = v; ri = vi; }
      else if (lane > pos){ rd = prd; ri = pri; }
      r31d = __shfl(rd, 31); r31i = __shfl(ri, 31);
    }
  }
  if (lane < K_) knn[(size_t)cg * K_ + lane] = ri;
}

// ---------------------------------------------------------------------------
// Conv stack helpers. Wave-private X tile [32 cols][136 ch] bf16 in LDS.
// MFMA 16x16x32 bf16: A[m=lane&15][k=q*8+j], B[k=q*8+j][n=lane&15],
// D col=lane&15, row=q*4+reg (m89-verified layouts). W is bf16 (pre-converted).
// ---------------------------------------------------------------------------
__device__ __forceinline__ void zero_acc(f32x4 acc[8][2]){
  #pragma unroll
  for (int mt = 0; mt < 8; ++mt)
    #pragma unroll
    for (int nt = 0; nt < 2; ++nt){
      acc[mt][nt][0] = 0.f; acc[mt][nt][1] = 0.f; acc[mt][nt][2] = 0.f; acc[mt][nt][3] = 0.f;
    }
}

__device__ __forceinline__ void conv_step(const u16* __restrict__ W, const u16* __restrict__ Xw,
                                          int q, int l15, f32x4 acc[8][2]){
  #pragma unroll
  for (int kk = 0; kk < 4; ++kk){
    short8 b0 = *(const short8*)(Xw + l15*LDSPAD + kk*32 + q*8);
    short8 b1 = *(const short8*)(Xw + (16 + l15)*LDSPAD + kk*32 + q*8);
    #pragma unroll
    for (int mt = 0; mt < 8; ++mt){
      short8 a = *(const short8*)(W + (size_t)(mt*16 + l15)*COUT + kk*32 + q*8);
      acc[mt][0] = MFMA16(a, b0, acc[mt][0]);
      acc[mt][1] = MFMA16(a, b1, acc[mt][1]);
    }
  }
}

// y1 = relu(bn1(W1@X)); out = relu(bn2(W2@y1) + resid). Leaves post-relu f32 in acc.
__device__ __forceinline__ void res_block(const u16* __restrict__ W1, const u16* __restrict__ W2,
    const float* __restrict__ bn1, const float* __restrict__ bn2,
    u16* __restrict__ Xw, int q, int l15, u32 resid[8][2][2], f32x4 acc[8][2], bool writeback){
  zero_acc(acc);
  conv_step(W1, Xw, q, l15, acc);
  #pragma unroll
  for (int mt = 0; mt < 8; ++mt){
    f32x4 sc = *(const f32x4*)(bn1 + mt*16 + q*4);
    f32x4 bi = *(const f32x4*)(bn1 + 128 + mt*16 + q*4);
    #pragma unroll
    for (int nt = 0; nt < 2; ++nt){
      float y0 = fmaxf(fmaf(acc[mt][nt][0], sc[0], bi[0]), 0.f);
      float y1 = fmaxf(fmaf(acc[mt][nt][1], sc[1], bi[1]), 0.f);
      float y2 = fmaxf(fmaf(acc[mt][nt][2], sc[2], bi[2]), 0.f);
      float y3 = fmaxf(fmaf(acc[mt][nt][3], sc[3], bi[3]), 0.f);
      *(uint2*)(Xw + (nt*16 + l15)*LDSPAD + mt*16 + q*4) = make_uint2(pack2bf(y0,y1), pack2bf(y2,y3));
    }
  }
  __syncthreads();
  zero_acc(acc);
  conv_step(W2, Xw, q, l15, acc);
  #pragma unroll
  for (int mt = 0; mt < 8; ++mt){
    f32x4 sc = *(const f32x4*)(bn2 + mt*16 + q*4);
    f32x4 bi = *(const f32x4*)(bn2 + 128 + mt*16 + q*4);
    #pragma unroll
    for (int nt = 0; nt < 2; ++nt){
      float r0 = bf2f((u16)(resid[mt][nt][0] & 0xFFFFu));
      float r1 = bf2f((u16)(resid[mt][nt][0] >> 16));
      float r2 = bf2f((u16)(resid[mt][nt][1] & 0xFFFFu));
      float r3 = bf2f((u16)(resid[mt][nt][1] >> 16));
      float y0 = fmaxf(fmaf(acc[mt][nt][0], sc[0], bi[0]) + r0, 0.f);
      float y1 = fmaxf(fmaf(acc[mt][nt][1], sc[1], bi[1]) + r1, 0.f);
      float y2 = fmaxf(fmaf(acc[mt][nt][2], sc[2], bi[2]) + r2, 0.f);
      float y3 = fmaxf(fmaf(acc[mt][nt][3], sc[3], bi[3]) + r3, 0.f);
      acc[mt][nt][0] = y0; acc[mt][nt][1] = y1; acc[mt][nt][2] = y2; acc[mt][nt][3] = y3;
      if (writeback){
        u32 p0 = pack2bf(y0,y1), p1 = pack2bf(y2,y3);
        resid[mt][nt][0] = p0; resid[mt][nt][1] = p1;
        *(uint2*)(Xw + (nt*16 + l15)*LDSPAD + mt*16 + q*4) = make_uint2(p0, p1);
      }
    }
  }
  if (writeback) __syncthreads();
}

// ---------------------------------------------------------------------------
// mid: gather(knn, f32 feat -> bf16) -> te conv -> 2 pre res-blocks -> maxpool.
// One wave per center; 4 waves/block. Output x_mid[g][128] bf16 (ws).
// ---------------------------------------------------------------------------
__global__ __launch_bounds__(256) void mid_kernel(const float* __restrict__ feat,
    const u16* __restrict__ te_w, const u16* __restrict__ pre_w1, const u16* __restrict__ pre_w2,
    const float* __restrict__ bns, const int* __restrict__ fps_idx, const int* __restrict__ knn,
    u16* __restrict__ x_mid){
  __shared__ __align__(16) u16 X[4][32*LDSPAD];
  __shared__ __align__(16) float scr[4][128];
  const int wid = threadIdx.x >> 6, lane = threadIdx.x & 63;
  const int q = lane >> 4, l15 = lane & 15;
  const int g = blockIdx.x*4 + wid;
  const int b = g >> 11;
  const float* fb = feat + (size_t)b * N_ * CIN;
  u16* Xw = X[wid];

  const int ctr = fps_idx[g] & (N_ - 1);
  const int* kg = knn + (size_t)g * K_;
  #pragma unroll
  for (int it = 0; it < 4; ++it){
    int lidx = it*64 + lane;
    int col = lidx >> 3, kq = lidx & 7;           // col<32, 8-ch chunk kq<8
    int nb = kg[col] & (N_ - 1);
    f32x4 a0 = *(const f32x4*)(fb + (size_t)nb*CIN + kq*8);
    f32x4 a1 = *(const f32x4*)(fb + (size_t)nb*CIN + kq*8 + 4);
    *(uint2*)(Xw + col*LDSPAD + kq*8)     = make_uint2(pack2bf(a0[0],a0[1]), pack2bf(a0[2],a0[3]));
    *(uint2*)(Xw + col*LDSPAD + kq*8 + 4) = make_uint2(pack2bf(a1[0],a1[1]), pack2bf(a1[2],a1[3]));
    f32x4 c0 = *(const f32x4*)(fb + (size_t)ctr*CIN + kq*8);
    f32x4 c1 = *(const f32x4*)(fb + (size_t)ctr*CIN + kq*8 + 4);
    *(uint2*)(Xw + col*LDSPAD + 64 + kq*8)     = make_uint2(pack2bf(c0[0],c0[1]), pack2bf(c0[2],c0[3]));
    *(uint2*)(Xw + col*LDSPAD + 64 + kq*8 + 4) = make_uint2(pack2bf(c1[0],c1[1]), pack2bf(c1[2],c1[3]));
  }
  __syncthreads();

  f32x4 acc[8][2];
  u32 resid[8][2][2];
  zero_acc(acc);
  conv_step(te_w, Xw, q, l15, acc);
  #pragma unroll
  for (int mt = 0; mt < 8; ++mt){
    f32x4 sc = *(const f32x4*)(bns + mt*16 + q*4);
    f32x4 bi = *(const f32x4*)(bns + 128 + mt*16 + q*4);
    #pragma unroll
    for (int nt = 0; nt < 2; ++nt){
      float y0 = fmaxf(fmaf(acc[mt][nt][0], sc[0], bi[0]), 0.f);
      float y1 = fmaxf(fmaf(acc[mt][nt][1], sc[1], bi[1]), 0.f);
      float y2 = fmaxf(fmaf(acc[mt][nt][2], sc[2], bi[2]), 0.f);
      float y3 = fmaxf(fmaf(acc[mt][nt][3], sc[3], bi[3]), 0.f);
      u32 p0 = pack2bf(y0,y1), p1 = pack2bf(y2,y3);
      resid[mt][nt][0] = p0; resid[mt][nt][1] = p1;
      *(uint2*)(Xw + (nt*16 + l15)*LDSPAD + mt*16 + q*4) = make_uint2(p0, p1);
    }
  }
  __syncthreads();

  res_block(pre_w1,             pre_w2,             bns + 256, bns + 512,  Xw, q, l15, resid, acc, true);
  res_block(pre_w1 + COUT*COUT, pre_w2 + COUT*COUT, bns + 768, bns + 1024, Xw, q, l15, resid, acc, false);

  // maxpool over 32 cols (nt pair + butterfly over low-4 lane bits)
  float mx[8][4];
  #pragma unroll
  for (int mt = 0; mt < 8; ++mt)
    #pragma unroll
    for (int r = 0; r < 4; ++r){
      float m0 = fmaxf(acc[mt][0][r], acc[mt][1][r]);
      #pragma unroll
      for (int off = 1; off < 16; off <<= 1) m0 = fmaxf(m0, __shfl_xor(m0, off));
      mx[mt][r] = m0;
    }
  if (l15 == 0){
    #pragma unroll
    for (int mt = 0; mt < 8; ++mt){
      f32x4 vv; vv[0] = mx[mt][0]; vv[1] = mx[mt][1]; vv[2] = mx[mt][2]; vv[3] = mx[mt][3];
      *(f32x4*)(scr[wid] + mt*16 + q*4) = vv;
    }
  }
  __syncthreads();
  float v0 = scr[wid][lane*2], v1 = scr[wid][lane*2 + 1];
  *(u32*)(x_mid + (size_t)g*COUT + lane*2) = pack2bf(v0, v1);
}

// ---------------------------------------------------------------------------
// pos: 2 res-blocks over (B,128,2048); one wave per 32 columns. f32 out.
// ---------------------------------------------------------------------------
__global__ __launch_bounds__(256) void pos_kernel(const u16* __restrict__ x_mid,
    const u16* __restrict__ pos_w1, const u16* __restrict__ pos_w2,
    const float* __restrict__ bns, float* __restrict__ out_x){
  __shared__ __align__(16) u16 X[4][32*LDSPAD];
  const int wid = threadIdx.x >> 6, lane = threadIdx.x & 63;
  const int q = lane >> 4, l15 = lane & 15;
  const int g = blockIdx.x*4 + wid;            // 0..511
  const int gc0 = g * 32;
  const int b = gc0 >> 11, s0 = gc0 & 2047;
  u16* Xw = X[wid];
  #pragma unroll
  for (int it = 0; it < 8; ++it){
    int lidx = it*64 + lane;
    int col = lidx >> 4, kq = lidx & 15;
    uint4 v = *(const uint4*)(x_mid + (size_t)(gc0 + col)*COUT + kq*8);
    *(uint4*)(Xw + col*LDSPAD + kq*8) = v;
  }
  __syncthreads();
  u32 resid[8][2][2];
  #pragma unroll
  for (int mt = 0; mt < 8; ++mt)
    #pragma unroll
    for (int nt = 0; nt < 2; ++nt){
      uint2 rr = *(const uint2*)(Xw + (nt*16 + l15)*LDSPAD + mt*16 + q*4);
      resid[mt][nt][0] = rr.x; resid[mt][nt][1] = rr.y;
    }
  f32x4 acc[8][2];
  res_block(pos_w1,             pos_w2,             bns + 1280, bns + 1536, Xw, q, l15, resid, acc, true);
  res_block(pos_w1 + COUT*COUT, pos_w2 + COUT*COUT, bns + 1792, bns + 2048, Xw, q, l15, resid, acc, false);
  #pragma unroll
  for (int mt = 0; mt < 8; ++mt)
    #pragma unroll
    for (int nt = 0; nt < 2; ++nt)
      #pragma unroll
      for (int r = 0; r < 4; ++r){
        int row = mt*16 + q*4 + r;
        int colx = s0 + nt*16 + l15;
        out_x[(size_t)(b*COUT + row)*NS + colx] = acc[mt][nt][r];
      }
}

// ---------------------------------------------------------------------------
extern "C" void kernel_launch(void* const* d_in, const int* in_sizes, int n_in,
                              void* d_out, int out_size, void* d_ws, size_t ws_size,
                              hipStream_t stream){
  (void)in_sizes; (void)n_in; (void)out_size; (void)ws_size;
  const float* xyz    = (const float*)d_in[0];
  const float* feat   = (const float*)d_in[1];

  // ws layout (16B aligned, ~6.4 MB total):
  char* ws = (char*)d_ws;
  float* bns     = (float*)ws;                          // 16 KiB (9.2 used)
  u16*   wbf     = (u16*)(ws + 16384);                  // 288 KiB bf16 weights
  int*   fps_idx = (int*)(ws + 16384 + 294912);         // 64 KiB
  int*   knn     = (int*)(ws + 16384 + 294912 + 65536); // 2 MiB
  u16*   x_mid   = (u16*)(ws + 16384 + 294912 + 65536 + 2097152); // 4 MiB
  float* out_xyz = (float*)d_out;                       // (8,2048,3) f32
  float* out_x   = (float*)d_out + B_*NS*3;             // (8,128,2048) f32

  // bf16 weight staging: te(16384) pre_w1(32768) pre_w2(32768) pos_w1(32768) pos_w2(32768)
  u16* te_w   = wbf;
  u16* pre_w1 = wbf + 16384;
  u16* pre_w2 = wbf + 49152;
  u16* pos_w1 = wbf + 81920;
  u16* pos_w2 = wbf + 114688;
  wcvt_kernel<<<64,  256, 0, stream>>>((const float*)d_in[2],  te_w,   16384);
  wcvt_kernel<<<128, 256, 0, stream>>>((const float*)d_in[7],  pre_w1, 32768);
  wcvt_kernel<<<128, 256, 0, stream>>>((const float*)d_in[8],  pre_w2, 32768);
  wcvt_kernel<<<128, 256, 0, stream>>>((const float*)d_in[17], pos_w1, 32768);
  wcvt_kernel<<<128, 256, 0, stream>>>((const float*)d_in[18], pos_w2, 32768);

  // dict order: te_g/b/m/v = 3..6 ; pre: w1,w2,g1,g2,b1,b2,m1,m2,v1,v2 = 7..16 ; pos = 17..26
  BnPtrs bp;
  const int gi[9] = {3, 9, 10, 9, 10, 19, 20, 19, 20};
  const int bbi[9]= {4, 11,12, 11,12, 21, 22, 21, 22};
  const int mi[9] = {5, 13,14, 13,14, 23, 24, 23, 24};
  const int vi[9] = {6, 15,16, 15,16, 25, 26, 25, 26};
  const int of[9] = {0, 0, 0, 128,128, 0, 0, 128,128};
  for (int k = 0; k < 9; ++k){
    bp.g[k] = (const float*)d_in[gi[k]]  + of[k];
    bp.b[k] = (const float*)d_in[bbi[k]] + of[k];
    bp.m[k] = (const float*)d_in[mi[k]]  + of[k];
    bp.v[k] = (const float*)d_in[vi[k]]  + of[k];
  }

  bn_pre_kernel<<<9, 128, 0, stream>>>(bp, bns);
  fps_kernel<<<B_, 512, 0, stream>>>(xyz, fps_idx);
  knn_kernel<<<(B_*NS)/4, 256, 0, stream>>>(xyz, fps_idx, knn, out_xyz);
  mid_kernel<<<(B_*NS)/4, 256, 0, stream>>>(feat, te_w, pre_w1, pre_w2, bns, fps_idx, knn, x_mid);
  pos_kernel<<<(B_*NS/K_)/4, 256, 0, stream>>>(x_mid, pos_w1, pos_w2, bns, out_x);
}

// Round 7
// 3811.190 us; speedup vs baseline: 1.1568x; 1.1543x over previous
//
#include <hip/hip_runtime.h>

typedef unsigned short u16;
typedef unsigned int   u32;
typedef unsigned long long u64;

#define B_    8
#define N_    8192
#define CIN   64
#define COUT  128
#define NS    2048
#define K_    32
#define LDSPAD 136   // 128 + 8 bf16: breaks bank conflicts on column stride

typedef __attribute__((ext_vector_type(8))) short short8;
typedef __attribute__((ext_vector_type(4))) float f32x4;

#define MFMA16(a,b,c) __builtin_amdgcn_mfma_f32_16x16x32_bf16(a,b,c,0,0,0)

__device__ __forceinline__ u16 f2bf(float f){
  u32 u = __float_as_uint(f);
  return (u16)((u + 0x7FFFu + ((u >> 16) & 1u)) >> 16);   // RNE, finite values only
}
__device__ __forceinline__ float bf2f(u16 h){ u32 u = ((u32)h) << 16; return __uint_as_float(u); }
__device__ __forceinline__ u32 pack2bf(float lo, float hi){ return (u32)f2bf(lo) | ((u32)f2bf(hi) << 16); }

// ---------------------------------------------------------------------------
// Weight f32 -> bf16 conversion (one-time prep into ws)
// ---------------------------------------------------------------------------
__global__ void wcvt_kernel(const float* __restrict__ s, u16* __restrict__ d, int n){
  int i = blockIdx.x * 256 + threadIdx.x;
  if (i < n) d[i] = f2bf(s[i]);
}

// ---------------------------------------------------------------------------
// BN constants: scale = g/sqrt(v+eps), bias = b - m*scale  (all f32 inputs)
// set order: 0=te, 1/2=pre0.bn1/bn2, 3/4=pre1.bn1/bn2, 5/6=pos0, 7/8=pos1
// ---------------------------------------------------------------------------
struct BnPtrs { const float* g[9]; const float* b[9]; const float* m[9]; const float* v[9]; };

__global__ void bn_pre_kernel(BnPtrs p, float* __restrict__ bns){
  int set = blockIdx.x, c = threadIdx.x;
  float sc = p.g[set][c] / sqrtf(p.v[set][c] + 1e-5f);
  bns[set*256 + c]       = sc;
  bns[set*256 + 128 + c] = p.b[set][c] - p.m[set][c] * sc;
}

// ---------------------------------------------------------------------------
// FPS: 1 block / batch, 1024 threads, 8 pts/thread.
// r3-r6 lesson: with 16 pts/thread (64 array floats) the allocator refuses
// register residency at every occupancy hint (VGPR 48/76/88, FETCH ~420 MB
// of per-step re-loads). 8 pts/thread needs only 32 array floats (~55 live
// total) — below even the most aggressive 64-VGPR allocation target, so
// registers win at any occupancy the compiler picks. 16 waves/CU also
// halves per-SIMD issue time for the fixed 8192-pt distance workload.
// Serial tail = r3 style (fastest measured): winner index from packed-u64
// LDS scan, winner coords re-read from global (L1-hot broadcast).
// Exact f32 (contract off) to bit-match np; argmax tie -> lowest index.
// ---------------------------------------------------------------------------
__global__ __launch_bounds__(1024) void fps_kernel(const float* __restrict__ xyz, int* __restrict__ fps_idx){
  #pragma clang fp contract(off)
  const int b = blockIdx.x;
  const int t = threadIdx.x;
  const float* xb = xyz + (size_t)b * N_ * 3;
  float px[8], py[8], pz[8], dist[8];
  const int base = t * 8;
  #pragma unroll
  for (int j = 0; j < 8; ++j){
    px[j] = xb[(base + j)*3 + 0];
    py[j] = xb[(base + j)*3 + 1];
    pz[j] = xb[(base + j)*3 + 2];
    dist[j] = 1e10f;
  }
  __shared__ u64 kArr[2][16];
  if (t == 0) fps_idx[b*NS] = 0;
  float lx = xb[0], ly = xb[1], lz = xb[2];     // point 0 is the seed
  for (int s = 0; s < NS - 1; ++s){
    float bv = -1.0f; int bi = 0;
    #pragma unroll
    for (int j = 0; j < 8; ++j){
      float dx = px[j] - lx;
      float dy = py[j] - ly;
      float dz = pz[j] - lz;
      float t0 = dx*dx;
      float t1 = dy*dy;
      float t2 = dz*dz;
      float dd = (t0 + t1) + t2;                // same assoc as np.sum axis=-1
      float nd = fminf(dist[j], dd);
      dist[j] = nd;
      bool c = nd > bv;                         // strict > keeps earliest index
      bv = c ? nd : bv; bi = c ? base + j : bi;
    }
    #pragma unroll
    for (int off = 1; off < 64; off <<= 1){
      float ov = __shfl_xor(bv, off);
      int   oi = __shfl_xor(bi, off);
      bool c = (ov > bv) || (ov == bv && oi < bi);
      bv = c ? ov : bv; bi = c ? oi : bi;
    }
    const int sl = s & 1;
    if ((t & 63) == 0)
      kArr[sl][t >> 6] = ((u64)__float_as_uint(bv) << 13) | (u64)(8191 - bi);
    __syncthreads();
    u64 win = kArr[sl][0];
    #pragma unroll
    for (int w = 1; w < 16; ++w){ u64 o = kArr[sl][w]; if (o > win) win = o; }
    const int last = 8191 - (int)(win & 0x1FFFull);   // structurally in [0,8191]
    lx = xb[last*3]; ly = xb[last*3 + 1]; lz = xb[last*3 + 2];  // L1-hot broadcast
    if (t == 0) fps_idx[b*NS + s + 1] = last;
  }
}

// ---------------------------------------------------------------------------
// kNN: one wave per center, sorted 64-slot (d2,idx) lane-list, threshold =
// slot 31. Ballot pre-filter per 64-pt chunk, shfl_up sorted insertion.
// Exact f32 distances + lex (d2,idx) ties == stable top_k neighbor set.
// Also emits new_xyz (exact f32 gather).
// ---------------------------------------------------------------------------
__global__ __launch_bounds__(256) void knn_kernel(const float* __restrict__ xyz, const int* __restrict__ fps_idx,
                                                  int* __restrict__ knn, float* __restrict__ out_xyz){
  #pragma clang fp contract(off)
  const int wid = threadIdx.x >> 6, lane = threadIdx.x & 63;
  const int cg = blockIdx.x * 4 + wid;
  const int b = cg >> 11;
  const float* xb = xyz + (size_t)b * N_ * 3;
  const int ci = fps_idx[cg] & (N_ - 1);      // clamp: fault-proof
  const float cx = xb[ci*3], cy = xb[ci*3+1], cz = xb[ci*3+2];
  if (lane < 3) out_xyz[cg*3 + lane] = xb[ci*3 + lane];

  float rd = __uint_as_float(0x7F800000u); int ri = 0x7FFFFFFF;
  float r31d = rd; int r31i = ri;
  for (int c = 0; c < N_/64; ++c){
    const int pid = c*64 + lane;
    float dx = xb[pid*3]   - cx;
    float dy = xb[pid*3+1] - cy;
    float dz = xb[pid*3+2] - cz;
    float t0 = dx*dx, t1 = dy*dy, t2 = dz*dz;
    float d2 = (t0 + t1) + t2;
    u64 m = __ballot((d2 < r31d) || (d2 == r31d && pid < r31i));
    while (m){
      int l = __ffsll((long long)m) - 1; m &= m - 1;
      float v = __shfl(d2, l); int vi = c*64 + l;
      if (!((v < r31d) || (v == r31d && vi < r31i))) continue;  // re-check vs updated threshold
      bool lt = (rd < v) || (rd == v && ri < vi);
      int pos = __popcll(__ballot(lt));
      float prd = __shfl_up(rd, 1); int pri = __shfl_up(ri, 1);
      if (lane == pos){ rd = v; ri = vi; }
      else if (lane > pos){ rd = prd; ri = pri; }
      r31d = __shfl(rd, 31); r31i = __shfl(ri, 31);
    }
  }
  if (lane < K_) knn[(size_t)cg * K_ + lane] = ri;
}

// ---------------------------------------------------------------------------
// Conv stack helpers. Wave-private X tile [32 cols][136 ch] bf16 in LDS.
// MFMA 16x16x32 bf16: A[m=lane&15][k=q*8+j], B[k=q*8+j][n=lane&15],
// D col=lane&15, row=q*4+reg (m89-verified layouts). W is bf16 (pre-converted).
// ---------------------------------------------------------------------------
__device__ __forceinline__ void zero_acc(f32x4 acc[8][2]){
  #pragma unroll
  for (int mt = 0; mt < 8; ++mt)
    #pragma unroll
    for (int nt = 0; nt < 2; ++nt){
      acc[mt][nt][0] = 0.f; acc[mt][nt][1] = 0.f; acc[mt][nt][2] = 0.f; acc[mt][nt][3] = 0.f;
    }
}

__device__ __forceinline__ void conv_step(const u16* __restrict__ W, const u16* __restrict__ Xw,
                                          int q, int l15, f32x4 acc[8][2]){
  #pragma unroll
  for (int kk = 0; kk < 4; ++kk){
    short8 b0 = *(const short8*)(Xw + l15*LDSPAD + kk*32 + q*8);
    short8 b1 = *(const short8*)(Xw + (16 + l15)*LDSPAD + kk*32 + q*8);
    #pragma unroll
    for (int mt = 0; mt < 8; ++mt){
      short8 a = *(const short8*)(W + (size_t)(mt*16 + l15)*COUT + kk*32 + q*8);
      acc[mt][0] = MFMA16(a, b0, acc[mt][0]);
      acc[mt][1] = MFMA16(a, b1, acc[mt][1]);
    }
  }
}

// y1 = relu(bn1(W1@X)); out = relu(bn2(W2@y1) + resid). Leaves post-relu f32 in acc.
__device__ __forceinline__ void res_block(const u16* __restrict__ W1, const u16* __restrict__ W2,
    const float* __restrict__ bn1, const float* __restrict__ bn2,
    u16* __restrict__ Xw, int q, int l15, u32 resid[8][2][2], f32x4 acc[8][2], bool writeback){
  zero_acc(acc);
  conv_step(W1, Xw, q, l15, acc);
  #pragma unroll
  for (int mt = 0; mt < 8; ++mt){
    f32x4 sc = *(const f32x4*)(bn1 + mt*16 + q*4);
    f32x4 bi = *(const f32x4*)(bn1 + 128 + mt*16 + q*4);
    #pragma unroll
    for (int nt = 0; nt < 2; ++nt){
      float y0 = fmaxf(fmaf(acc[mt][nt][0], sc[0], bi[0]), 0.f);
      float y1 = fmaxf(fmaf(acc[mt][nt][1], sc[1], bi[1]), 0.f);
      float y2 = fmaxf(fmaf(acc[mt][nt][2], sc[2], bi[2]), 0.f);
      float y3 = fmaxf(fmaf(acc[mt][nt][3], sc[3], bi[3]), 0.f);
      *(uint2*)(Xw + (nt*16 + l15)*LDSPAD + mt*16 + q*4) = make_uint2(pack2bf(y0,y1), pack2bf(y2,y3));
    }
  }
  __syncthreads();
  zero_acc(acc);
  conv_step(W2, Xw, q, l15, acc);
  #pragma unroll
  for (int mt = 0; mt < 8; ++mt){
    f32x4 sc = *(const f32x4*)(bn2 + mt*16 + q*4);
    f32x4 bi = *(const f32x4*)(bn2 + 128 + mt*16 + q*4);
    #pragma unroll
    for (int nt = 0; nt < 2; ++nt){
      float r0 = bf2f((u16)(resid[mt][nt][0] & 0xFFFFu));
      float r1 = bf2f((u16)(resid[mt][nt][0] >> 16));
      float r2 = bf2f((u16)(resid[mt][nt][1] & 0xFFFFu));
      float r3 = bf2f((u16)(resid[mt][nt][1] >> 16));
      float y0 = fmaxf(fmaf(acc[mt][nt][0], sc[0], bi[0]) + r0, 0.f);
      float y1 = fmaxf(fmaf(acc[mt][nt][1], sc[1], bi[1]) + r1, 0.f);
      float y2 = fmaxf(fmaf(acc[mt][nt][2], sc[2], bi[2]) + r2, 0.f);
      float y3 = fmaxf(fmaf(acc[mt][nt][3], sc[3], bi[3]) + r3, 0.f);
      acc[mt][nt][0] = y0; acc[mt][nt][1] = y1; acc[mt][nt][2] = y2; acc[mt][nt][3] = y3;
      if (writeback){
        u32 p0 = pack2bf(y0,y1), p1 = pack2bf(y2,y3);
        resid[mt][nt][0] = p0; resid[mt][nt][1] = p1;
        *(uint2*)(Xw + (nt*16 + l15)*LDSPAD + mt*16 + q*4) = make_uint2(p0, p1);
      }
    }
  }
  if (writeback) __syncthreads();
}

// ---------------------------------------------------------------------------
// mid: gather(knn, f32 feat -> bf16) -> te conv -> 2 pre res-blocks -> maxpool.
// One wave per center; 4 waves/block. Output x_mid[g][128] bf16 (ws).
// ---------------------------------------------------------------------------
__global__ __launch_bounds__(256) void mid_kernel(const float* __restrict__ feat,
    const u16* __restrict__ te_w, const u16* __restrict__ pre_w1, const u16* __restrict__ pre_w2,
    const float* __restrict__ bns, const int* __restrict__ fps_idx, const int* __restrict__ knn,
    u16* __restrict__ x_mid){
  __shared__ __align__(16) u16 X[4][32*LDSPAD];
  __shared__ __align__(16) float scr[4][128];
  const int wid = threadIdx.x >> 6, lane = threadIdx.x & 63;
  const int q = lane >> 4, l15 = lane & 15;
  const int g = blockIdx.x*4 + wid;
  const int b = g >> 11;
  const float* fb = feat + (size_t)b * N_ * CIN;
  u16* Xw = X[wid];

  const int ctr = fps_idx[g] & (N_ - 1);
  const int* kg = knn + (size_t)g * K_;
  #pragma unroll
  for (int it = 0; it < 4; ++it){
    int lidx = it*64 + lane;
    int col = lidx >> 3, kq = lidx & 7;           // col<32, 8-ch chunk kq<8
    int nb = kg[col] & (N_ - 1);
    f32x4 a0 = *(const f32x4*)(fb + (size_t)nb*CIN + kq*8);
    f32x4 a1 = *(const f32x4*)(fb + (size_t)nb*CIN + kq*8 + 4);
    *(uint2*)(Xw + col*LDSPAD + kq*8)     = make_uint2(pack2bf(a0[0],a0[1]), pack2bf(a0[2],a0[3]));
    *(uint2*)(Xw + col*LDSPAD + kq*8 + 4) = make_uint2(pack2bf(a1[0],a1[1]), pack2bf(a1[2],a1[3]));
    f32x4 c0 = *(const f32x4*)(fb + (size_t)ctr*CIN + kq*8);
    f32x4 c1 = *(const f32x4*)(fb + (size_t)ctr*CIN + kq*8 + 4);
    *(uint2*)(Xw + col*LDSPAD + 64 + kq*8)     = make_uint2(pack2bf(c0[0],c0[1]), pack2bf(c0[2],c0[3]));
    *(uint2*)(Xw + col*LDSPAD + 64 + kq*8 + 4) = make_uint2(pack2bf(c1[0],c1[1]), pack2bf(c1[2],c1[3]));
  }
  __syncthreads();

  f32x4 acc[8][2];
  u32 resid[8][2][2];
  zero_acc(acc);
  conv_step(te_w, Xw, q, l15, acc);
  #pragma unroll
  for (int mt = 0; mt < 8; ++mt){
    f32x4 sc = *(const f32x4*)(bns + mt*16 + q*4);
    f32x4 bi = *(const f32x4*)(bns + 128 + mt*16 + q*4);
    #pragma unroll
    for (int nt = 0; nt < 2; ++nt){
      float y0 = fmaxf(fmaf(acc[mt][nt][0], sc[0], bi[0]), 0.f);
      float y1 = fmaxf(fmaf(acc[mt][nt][1], sc[1], bi[1]), 0.f);
      float y2 = fmaxf(fmaf(acc[mt][nt][2], sc[2], bi[2]), 0.f);
      float y3 = fmaxf(fmaf(acc[mt][nt][3], sc[3], bi[3]), 0.f);
      u32 p0 = pack2bf(y0,y1), p1 = pack2bf(y2,y3);
      resid[mt][nt][0] = p0; resid[mt][nt][1] = p1;
      *(uint2*)(Xw + (nt*16 + l15)*LDSPAD + mt*16 + q*4) = make_uint2(p0, p1);
    }
  }
  __syncthreads();

  res_block(pre_w1,             pre_w2,             bns + 256, bns + 512,  Xw, q, l15, resid, acc, true);
  res_block(pre_w1 + COUT*COUT, pre_w2 + COUT*COUT, bns + 768, bns + 1024, Xw, q, l15, resid, acc, false);

  // maxpool over 32 cols (nt pair + butterfly over low-4 lane bits)
  float mx[8][4];
  #pragma unroll
  for (int mt = 0; mt < 8; ++mt)
    #pragma unroll
    for (int r = 0; r < 4; ++r){
      float m0 = fmaxf(acc[mt][0][r], acc[mt][1][r]);
      #pragma unroll
      for (int off = 1; off < 16; off <<= 1) m0 = fmaxf(m0, __shfl_xor(m0, off));
      mx[mt][r] = m0;
    }
  if (l15 == 0){
    #pragma unroll
    for (int mt = 0; mt < 8; ++mt){
      f32x4 vv; vv[0] = mx[mt][0]; vv[1] = mx[mt][1]; vv[2] = mx[mt][2]; vv[3] = mx[mt][3];
      *(f32x4*)(scr[wid] + mt*16 + q*4) = vv;
    }
  }
  __syncthreads();
  float v0 = scr[wid][lane*2], v1 = scr[wid][lane*2 + 1];
  *(u32*)(x_mid + (size_t)g*COUT + lane*2) = pack2bf(v0, v1);
}

// ---------------------------------------------------------------------------
// pos: 2 res-blocks over (B,128,2048); one wave per 32 columns. f32 out.
// ---------------------------------------------------------------------------
__global__ __launch_bounds__(256) void pos_kernel(const u16* __restrict__ x_mid,
    const u16* __restrict__ pos_w1, const u16* __restrict__ pos_w2,
    const float* __restrict__ bns, float* __restrict__ out_x){
  __shared__ __align__(16) u16 X[4][32*LDSPAD];
  const int wid = threadIdx.x >> 6, lane = threadIdx.x & 63;
  const int q = lane >> 4, l15 = lane & 15;
  const int g = blockIdx.x*4 + wid;            // 0..511
  const int gc0 = g * 32;
  const int b = gc0 >> 11, s0 = gc0 & 2047;
  u16* Xw = X[wid];
  #pragma unroll
  for (int it = 0; it < 8; ++it){
    int lidx = it*64 + lane;
    int col = lidx >> 4, kq = lidx & 15;
    uint4 v = *(const uint4*)(x_mid + (size_t)(gc0 + col)*COUT + kq*8);
    *(uint4*)(Xw + col*LDSPAD + kq*8) = v;
  }
  __syncthreads();
  u32 resid[8][2][2];
  #pragma unroll
  for (int mt = 0; mt < 8; ++mt)
    #pragma unroll
    for (int nt = 0; nt < 2; ++nt){
      uint2 rr = *(const uint2*)(Xw + (nt*16 + l15)*LDSPAD + mt*16 + q*4);
      resid[mt][nt][0] = rr.x; resid[mt][nt][1] = rr.y;
    }
  f32x4 acc[8][2];
  res_block(pos_w1,             pos_w2,             bns + 1280, bns + 1536, Xw, q, l15, resid, acc, true);
  res_block(pos_w1 + COUT*COUT, pos_w2 + COUT*COUT, bns + 1792, bns + 2048, Xw, q, l15, resid, acc, false);
  #pragma unroll
  for (int mt = 0; mt < 8; ++mt)
    #pragma unroll
    for (int nt = 0; nt < 2; ++nt)
      #pragma unroll
      for (int r = 0; r < 4; ++r){
        int row = mt*16 + q*4 + r;
        int colx = s0 + nt*16 + l15;
        out_x[(size_t)(b*COUT + row)*NS + colx] = acc[mt][nt][r];
      }
}

// ---------------------------------------------------------------------------
extern "C" void kernel_launch(void* const* d_in, const int* in_sizes, int n_in,
                              void* d_out, int out_size, void* d_ws, size_t ws_size,
                              hipStream_t stream){
  (void)in_sizes; (void)n_in; (void)out_size; (void)ws_size;
  const float* xyz    = (const float*)d_in[0];
  const float* feat   = (const float*)d_in[1];

  // ws layout (16B aligned, ~6.4 MB total):
  char* ws = (char*)d_ws;
  float* bns     = (float*)ws;                          // 16 KiB (9.2 used)
  u16*   wbf     = (u16*)(ws + 16384);                  // 288 KiB bf16 weights
  int*   fps_idx = (int*)(ws + 16384 + 294912);         // 64 KiB
  int*   knn     = (int*)(ws + 16384 + 294912 + 65536); // 2 MiB
  u16*   x_mid   = (u16*)(ws + 16384 + 294912 + 65536 + 2097152); // 4 MiB
  float* out_xyz = (float*)d_out;                       // (8,2048,3) f32
  float* out_x   = (float*)d_out + B_*NS*3;             // (8,128,2048) f32

  // bf16 weight staging: te(16384) pre_w1(32768) pre_w2(32768) pos_w1(32768) pos_w2(32768)
  u16* te_w   = wbf;
  u16* pre_w1 = wbf + 16384;
  u16* pre_w2 = wbf + 49152;
  u16* pos_w1 = wbf + 81920;
  u16* pos_w2 = wbf + 114688;
  wcvt_kernel<<<64,  256, 0, stream>>>((const float*)d_in[2],  te_w,   16384);
  wcvt_kernel<<<128, 256, 0, stream>>>((const float*)d_in[7],  pre_w1, 32768);
  wcvt_kernel<<<128, 256, 0, stream>>>((const float*)d_in[8],  pre_w2, 32768);
  wcvt_kernel<<<128, 256, 0, stream>>>((const float*)d_in[17], pos_w1, 32768);
  wcvt_kernel<<<128, 256, 0, stream>>>((const float*)d_in[18], pos_w2, 32768);

  // dict order: te_g/b/m/v = 3..6 ; pre: w1,w2,g1,g2,b1,b2,m1,m2,v1,v2 = 7..16 ; pos = 17..26
  BnPtrs bp;
  const int gi[9] = {3, 9, 10, 9, 10, 19, 20, 19, 20};
  const int bbi[9]= {4, 11,12, 11,12, 21, 22, 21, 22};
  const int mi[9] = {5, 13,14, 13,14, 23, 24, 23, 24};
  const int vi[9] = {6, 15,16, 15,16, 25, 26, 25, 26};
  const int of[9] = {0, 0, 0, 128,128, 0, 0, 128,128};
  for (int k = 0; k < 9; ++k){
    bp.g[k] = (const float*)d_in[gi[k]]  + of[k];
    bp.b[k] = (const float*)d_in[bbi[k]] + of[k];
    bp.m[k] = (const float*)d_in[mi[k]]  + of[k];
    bp.v[k] = (const float*)d_in[vi[k]]  + of[k];
  }

  bn_pre_kernel<<<9, 128, 0, stream>>>(bp, bns);
  fps_kernel<<<B_, 1024, 0, stream>>>(xyz, fps_idx);
  knn_kernel<<<(B_*NS)/4, 256, 0, stream>>>(xyz, fps_idx, knn, out_xyz);
  mid_kernel<<<(B_*NS)/4, 256, 0, stream>>>(feat, te_w, pre_w1, pre_w2, bns, fps_idx, knn, x_mid);
  pos_kernel<<<(B_*NS/K_)/4, 256, 0, stream>>>(x_mid, pos_w1, pos_w2, bns, out_x);
}

// Round 8
// 3596.818 us; speedup vs baseline: 1.2258x; 1.0596x over previous
//
#include <hip/hip_runtime.h>

typedef unsigned short u16;
typedef unsigned int   u32;
typedef unsigned long long u64;

#define B_    8
#define N_    8192
#define CIN   64
#define COUT  128
#define NS    2048
#define K_    32
#define LDSPAD 136   // 128 + 8 bf16: breaks bank conflicts on column stride

typedef __attribute__((ext_vector_type(8))) short short8;
typedef __attribute__((ext_vector_type(4))) float f32x4;

#define MFMA16(a,b,c) __builtin_amdgcn_mfma_f32_16x16x32_bf16(a,b,c,0,0,0)

__device__ __forceinline__ u16 f2bf(float f){
  u32 u = __float_as_uint(f);
  return (u16)((u + 0x7FFFu + ((u >> 16) & 1u)) >> 16);   // RNE, finite values only
}
__device__ __forceinline__ float bf2f(u16 h){ u32 u = ((u32)h) << 16; return __uint_as_float(u); }
__device__ __forceinline__ u32 pack2bf(float lo, float hi){ return (u32)f2bf(lo) | ((u32)f2bf(hi) << 16); }

// ---------------------------------------------------------------------------
// Weight f32 -> bf16 conversion (one-time prep into ws)
// ---------------------------------------------------------------------------
__global__ void wcvt_kernel(const float* __restrict__ s, u16* __restrict__ d, int n){
  int i = blockIdx.x * 256 + threadIdx.x;
  if (i < n) d[i] = f2bf(s[i]);
}

// ---------------------------------------------------------------------------
// BN constants: scale = g/sqrt(v+eps), bias = b - m*scale  (all f32 inputs)
// set order: 0=te, 1/2=pre0.bn1/bn2, 3/4=pre1.bn1/bn2, 5/6=pos0, 7/8=pos1
// ---------------------------------------------------------------------------
struct BnPtrs { const float* g[9]; const float* b[9]; const float* m[9]; const float* v[9]; };

__global__ void bn_pre_kernel(BnPtrs p, float* __restrict__ bns){
  int set = blockIdx.x, c = threadIdx.x;
  float sc = p.g[set][c] / sqrtf(p.v[set][c] + 1e-5f);
  bns[set*256 + c]       = sc;
  bns[set*256 + 128 + c] = p.b[set][c] - p.m[set][c] * sc;
}

// ---------------------------------------------------------------------------
// FPS: 1 block / batch, 512 threads, 16 pts/thread as NAMED SCALARS.
// ERRATA r3-r7: FETCH_SIZE is KB (412 KB = the xyz input, L3-absorbed) —
// there was no HBM thrash. Real diagnosis: VGPR=32..88 with 32-64 array
// floats => px/py/pz/dist arrays were never SROA-promoted (scratch-resident,
// L1/L2-cached), so each step pays cached re-load + addr-calc + waitcnt per
// access => VALU ~79% busy on active CUs, 1.5-1.8 us/step. Fix: individual
// scalar variables (X0..X15,...) — SSA values from birth, guaranteed VGPR
// residency (~90 live, fits any allocator target). Exact f32 (contract off)
// to bit-match np; argmax tie -> lowest index.
// ---------------------------------------------------------------------------
#define FPS_LOAD(k) \
  X##k = xb[(base + k)*3 + 0]; Y##k = xb[(base + k)*3 + 1]; Z##k = xb[(base + k)*3 + 2]; D##k = 1e10f;

#define FPS_STEP(k) { \
  float dx = X##k - lx; \
  float dy = Y##k - ly; \
  float dz = Z##k - lz; \
  float t0 = dx*dx; \
  float t1 = dy*dy; \
  float t2 = dz*dz; \
  float dd = (t0 + t1) + t2;  /* same assoc as np.sum axis=-1 */ \
  float nd = fminf(D##k, dd); \
  D##k = nd; \
  bool c = nd > bv;           /* strict > keeps earliest index */ \
  bv = c ? nd : bv; bi = c ? (base + k) : bi; }

__global__ __launch_bounds__(512) void fps_kernel(const float* __restrict__ xyz, int* __restrict__ fps_idx){
  #pragma clang fp contract(off)
  const int b = blockIdx.x;
  const int t = threadIdx.x;
  const float* xb = xyz + (size_t)b * N_ * 3;
  const int base = t * 16;
  float X0,X1,X2,X3,X4,X5,X6,X7,X8,X9,X10,X11,X12,X13,X14,X15;
  float Y0,Y1,Y2,Y3,Y4,Y5,Y6,Y7,Y8,Y9,Y10,Y11,Y12,Y13,Y14,Y15;
  float Z0,Z1,Z2,Z3,Z4,Z5,Z6,Z7,Z8,Z9,Z10,Z11,Z12,Z13,Z14,Z15;
  float D0,D1,D2,D3,D4,D5,D6,D7,D8,D9,D10,D11,D12,D13,D14,D15;
  FPS_LOAD(0)  FPS_LOAD(1)  FPS_LOAD(2)  FPS_LOAD(3)
  FPS_LOAD(4)  FPS_LOAD(5)  FPS_LOAD(6)  FPS_LOAD(7)
  FPS_LOAD(8)  FPS_LOAD(9)  FPS_LOAD(10) FPS_LOAD(11)
  FPS_LOAD(12) FPS_LOAD(13) FPS_LOAD(14) FPS_LOAD(15)
  __shared__ u64 kArr[2][8];
  if (t == 0) fps_idx[b*NS] = 0;
  float lx = xb[0], ly = xb[1], lz = xb[2];     // point 0 is the seed
  for (int s = 0; s < NS - 1; ++s){
    float bv = -1.0f; int bi = 0;
    FPS_STEP(0)  FPS_STEP(1)  FPS_STEP(2)  FPS_STEP(3)
    FPS_STEP(4)  FPS_STEP(5)  FPS_STEP(6)  FPS_STEP(7)
    FPS_STEP(8)  FPS_STEP(9)  FPS_STEP(10) FPS_STEP(11)
    FPS_STEP(12) FPS_STEP(13) FPS_STEP(14) FPS_STEP(15)
    #pragma unroll
    for (int off = 1; off < 64; off <<= 1){
      float ov = __shfl_xor(bv, off);
      int   oi = __shfl_xor(bi, off);
      bool c = (ov > bv) || (ov == bv && oi < bi);
      bv = c ? ov : bv; bi = c ? oi : bi;
    }
    const int sl = s & 1;
    if ((t & 63) == 0)
      kArr[sl][t >> 6] = ((u64)__float_as_uint(bv) << 13) | (u64)(8191 - bi);
    __syncthreads();
    u64 win = kArr[sl][0];
    #pragma unroll
    for (int w = 1; w < 8; ++w){ u64 o = kArr[sl][w]; if (o > win) win = o; }
    const int last = 8191 - (int)(win & 0x1FFFull);   // structurally in [0,8191]
    lx = xb[last*3]; ly = xb[last*3 + 1]; lz = xb[last*3 + 2];  // L1/L2-hot broadcast
    if (t == 0) fps_idx[b*NS + s + 1] = last;
  }
}

// ---------------------------------------------------------------------------
// kNN: one wave per center, sorted 64-slot (d2,idx) lane-list, threshold =
// slot 31. Ballot pre-filter per 64-pt chunk, shfl_up sorted insertion.
// Exact f32 distances + lex (d2,idx) ties == stable top_k neighbor set.
// Also emits new_xyz (exact f32 gather).
// ---------------------------------------------------------------------------
__global__ __launch_bounds__(256) void knn_kernel(const float* __restrict__ xyz, const int* __restrict__ fps_idx,
                                                  int* __restrict__ knn, float* __restrict__ out_xyz){
  #pragma clang fp contract(off)
  const int wid = threadIdx.x >> 6, lane = threadIdx.x & 63;
  const int cg = blockIdx.x * 4 + wid;
  const int b = cg >> 11;
  const float* xb = xyz + (size_t)b * N_ * 3;
  const int ci = fps_idx[cg] & (N_ - 1);      // clamp: fault-proof
  const float cx = xb[ci*3], cy = xb[ci*3+1], cz = xb[ci*3+2];
  if (lane < 3) out_xyz[cg*3 + lane] = xb[ci*3 + lane];

  float rd = __uint_as_float(0x7F800000u); int ri = 0x7FFFFFFF;
  float r31d = rd; int r31i = ri;
  for (int c = 0; c < N_/64; ++c){
    const int pid = c*64 + lane;
    float dx = xb[pid*3]   - cx;
    float dy = xb[pid*3+1] - cy;
    float dz = xb[pid*3+2] - cz;
    float t0 = dx*dx, t1 = dy*dy, t2 = dz*dz;
    float d2 = (t0 + t1) + t2;
    u64 m = __ballot((d2 < r31d) || (d2 == r31d && pid < r31i));
    while (m){
      int l = __ffsll((long long)m) - 1; m &= m - 1;
      float v = __shfl(d2, l); int vi = c*64 + l;
      if (!((v < r31d) || (v == r31d && vi < r31i))) continue;  // re-check vs updated threshold
      bool lt = (rd < v) || (rd == v && ri < vi);
      int pos = __popcll(__ballot(lt));
      float prd = __shfl_up(rd, 1); int pri = __shfl_up(ri, 1);
      if (lane == pos){ rd = v; ri = vi; }
      else if (lane > pos){ rd = prd; ri = pri; }
      r31d = __shfl(rd, 31); r31i = __shfl(ri, 31);
    }
  }
  if (lane < K_) knn[(size_t)cg * K_ + lane] = ri;
}

// ---------------------------------------------------------------------------
// Conv stack helpers. Wave-private X tile [32 cols][136 ch] bf16 in LDS.
// MFMA 16x16x32 bf16: A[m=lane&15][k=q*8+j], B[k=q*8+j][n=lane&15],
// D col=lane&15, row=q*4+reg (m89-verified layouts). W is bf16 (pre-converted).
// ---------------------------------------------------------------------------
__device__ __forceinline__ void zero_acc(f32x4 acc[8][2]){
  #pragma unroll
  for (int mt = 0; mt < 8; ++mt)
    #pragma unroll
    for (int nt = 0; nt < 2; ++nt){
      acc[mt][nt][0] = 0.f; acc[mt][nt][1] = 0.f; acc[mt][nt][2] = 0.f; acc[mt][nt][3] = 0.f;
    }
}

__device__ __forceinline__ void conv_step(const u16* __restrict__ W, const u16* __restrict__ Xw,
                                          int q, int l15, f32x4 acc[8][2]){
  #pragma unroll
  for (int kk = 0; kk < 4; ++kk){
    short8 b0 = *(const short8*)(Xw + l15*LDSPAD + kk*32 + q*8);
    short8 b1 = *(const short8*)(Xw + (16 + l15)*LDSPAD + kk*32 + q*8);
    #pragma unroll
    for (int mt = 0; mt < 8; ++mt){
      short8 a = *(const short8*)(W + (size_t)(mt*16 + l15)*COUT + kk*32 + q*8);
      acc[mt][0] = MFMA16(a, b0, acc[mt][0]);
      acc[mt][1] = MFMA16(a, b1, acc[mt][1]);
    }
  }
}

// y1 = relu(bn1(W1@X)); out = relu(bn2(W2@y1) + resid). Leaves post-relu f32 in acc.
__device__ __forceinline__ void res_block(const u16* __restrict__ W1, const u16* __restrict__ W2,
    const float* __restrict__ bn1, const float* __restrict__ bn2,
    u16* __restrict__ Xw, int q, int l15, u32 resid[8][2][2], f32x4 acc[8][2], bool writeback){
  zero_acc(acc);
  conv_step(W1, Xw, q, l15, acc);
  #pragma unroll
  for (int mt = 0; mt < 8; ++mt){
    f32x4 sc = *(const f32x4*)(bn1 + mt*16 + q*4);
    f32x4 bi = *(const f32x4*)(bn1 + 128 + mt*16 + q*4);
    #pragma unroll
    for (int nt = 0; nt < 2; ++nt){
      float y0 = fmaxf(fmaf(acc[mt][nt][0], sc[0], bi[0]), 0.f);
      float y1 = fmaxf(fmaf(acc[mt][nt][1], sc[1], bi[1]), 0.f);
      float y2 = fmaxf(fmaf(acc[mt][nt][2], sc[2], bi[2]), 0.f);
      float y3 = fmaxf(fmaf(acc[mt][nt][3], sc[3], bi[3]), 0.f);
      *(uint2*)(Xw + (nt*16 + l15)*LDSPAD + mt*16 + q*4) = make_uint2(pack2bf(y0,y1), pack2bf(y2,y3));
    }
  }
  __syncthreads();
  zero_acc(acc);
  conv_step(W2, Xw, q, l15, acc);
  #pragma unroll
  for (int mt = 0; mt < 8; ++mt){
    f32x4 sc = *(const f32x4*)(bn2 + mt*16 + q*4);
    f32x4 bi = *(const f32x4*)(bn2 + 128 + mt*16 + q*4);
    #pragma unroll
    for (int nt = 0; nt < 2; ++nt){
      float r0 = bf2f((u16)(resid[mt][nt][0] & 0xFFFFu));
      float r1 = bf2f((u16)(resid[mt][nt][0] >> 16));
      float r2 = bf2f((u16)(resid[mt][nt][1] & 0xFFFFu));
      float r3 = bf2f((u16)(resid[mt][nt][1] >> 16));
      float y0 = fmaxf(fmaf(acc[mt][nt][0], sc[0], bi[0]) + r0, 0.f);
      float y1 = fmaxf(fmaf(acc[mt][nt][1], sc[1], bi[1]) + r1, 0.f);
      float y2 = fmaxf(fmaf(acc[mt][nt][2], sc[2], bi[2]) + r2, 0.f);
      float y3 = fmaxf(fmaf(acc[mt][nt][3], sc[3], bi[3]) + r3, 0.f);
      acc[mt][nt][0] = y0; acc[mt][nt][1] = y1; acc[mt][nt][2] = y2; acc[mt][nt][3] = y3;
      if (writeback){
        u32 p0 = pack2bf(y0,y1), p1 = pack2bf(y2,y3);
        resid[mt][nt][0] = p0; resid[mt][nt][1] = p1;
        *(uint2*)(Xw + (nt*16 + l15)*LDSPAD + mt*16 + q*4) = make_uint2(p0, p1);
      }
    }
  }
  if (writeback) __syncthreads();
}

// ---------------------------------------------------------------------------
// mid: gather(knn, f32 feat -> bf16) -> te conv -> 2 pre res-blocks -> maxpool.
// One wave per center; 4 waves/block. Output x_mid[g][128] bf16 (ws).
// ---------------------------------------------------------------------------
__global__ __launch_bounds__(256) void mid_kernel(const float* __restrict__ feat,
    const u16* __restrict__ te_w, const u16* __restrict__ pre_w1, const u16* __restrict__ pre_w2,
    const float* __restrict__ bns, const int* __restrict__ fps_idx, const int* __restrict__ knn,
    u16* __restrict__ x_mid){
  __shared__ __align__(16) u16 X[4][32*LDSPAD];
  __shared__ __align__(16) float scr[4][128];
  const int wid = threadIdx.x >> 6, lane = threadIdx.x & 63;
  const int q = lane >> 4, l15 = lane & 15;
  const int g = blockIdx.x*4 + wid;
  const int b = g >> 11;
  const float* fb = feat + (size_t)b * N_ * CIN;
  u16* Xw = X[wid];

  const int ctr = fps_idx[g] & (N_ - 1);
  const int* kg = knn + (size_t)g * K_;
  #pragma unroll
  for (int it = 0; it < 4; ++it){
    int lidx = it*64 + lane;
    int col = lidx >> 3, kq = lidx & 7;           // col<32, 8-ch chunk kq<8
    int nb = kg[col] & (N_ - 1);
    f32x4 a0 = *(const f32x4*)(fb + (size_t)nb*CIN + kq*8);
    f32x4 a1 = *(const f32x4*)(fb + (size_t)nb*CIN + kq*8 + 4);
    *(uint2*)(Xw + col*LDSPAD + kq*8)     = make_uint2(pack2bf(a0[0],a0[1]), pack2bf(a0[2],a0[3]));
    *(uint2*)(Xw + col*LDSPAD + kq*8 + 4) = make_uint2(pack2bf(a1[0],a1[1]), pack2bf(a1[2],a1[3]));
    f32x4 c0 = *(const f32x4*)(fb + (size_t)ctr*CIN + kq*8);
    f32x4 c1 = *(const f32x4*)(fb + (size_t)ctr*CIN + kq*8 + 4);
    *(uint2*)(Xw + col*LDSPAD + 64 + kq*8)     = make_uint2(pack2bf(c0[0],c0[1]), pack2bf(c0[2],c0[3]));
    *(uint2*)(Xw + col*LDSPAD + 64 + kq*8 + 4) = make_uint2(pack2bf(c1[0],c1[1]), pack2bf(c1[2],c1[3]));
  }
  __syncthreads();

  f32x4 acc[8][2];
  u32 resid[8][2][2];
  zero_acc(acc);
  conv_step(te_w, Xw, q, l15, acc);
  #pragma unroll
  for (int mt = 0; mt < 8; ++mt){
    f32x4 sc = *(const f32x4*)(bns + mt*16 + q*4);
    f32x4 bi = *(const f32x4*)(bns + 128 + mt*16 + q*4);
    #pragma unroll
    for (int nt = 0; nt < 2; ++nt){
      float y0 = fmaxf(fmaf(acc[mt][nt][0], sc[0], bi[0]), 0.f);
      float y1 = fmaxf(fmaf(acc[mt][nt][1], sc[1], bi[1]), 0.f);
      float y2 = fmaxf(fmaf(acc[mt][nt][2], sc[2], bi[2]), 0.f);
      float y3 = fmaxf(fmaf(acc[mt][nt][3], sc[3], bi[3]), 0.f);
      u32 p0 = pack2bf(y0,y1), p1 = pack2bf(y2,y3);
      resid[mt][nt][0] = p0; resid[mt][nt][1] = p1;
      *(uint2*)(Xw + (nt*16 + l15)*LDSPAD + mt*16 + q*4) = make_uint2(p0, p1);
    }
  }
  __syncthreads();

  res_block(pre_w1,             pre_w2,             bns + 256, bns + 512,  Xw, q, l15, resid, acc, true);
  res_block(pre_w1 + COUT*COUT, pre_w2 + COUT*COUT, bns + 768, bns + 1024, Xw, q, l15, resid, acc, false);

  // maxpool over 32 cols (nt pair + butterfly over low-4 lane bits)
  float mx[8][4];
  #pragma unroll
  for (int mt = 0; mt < 8; ++mt)
    #pragma unroll
    for (int r = 0; r < 4; ++r){
      float m0 = fmaxf(acc[mt][0][r], acc[mt][1][r]);
      #pragma unroll
      for (int off = 1; off < 16; off <<= 1) m0 = fmaxf(m0, __shfl_xor(m0, off));
      mx[mt][r] = m0;
    }
  if (l15 == 0){
    #pragma unroll
    for (int mt = 0; mt < 8; ++mt){
      f32x4 vv; vv[0] = mx[mt][0]; vv[1] = mx[mt][1]; vv[2] = mx[mt][2]; vv[3] = mx[mt][3];
      *(f32x4*)(scr[wid] + mt*16 + q*4) = vv;
    }
  }
  __syncthreads();
  float v0 = scr[wid][lane*2], v1 = scr[wid][lane*2 + 1];
  *(u32*)(x_mid + (size_t)g*COUT + lane*2) = pack2bf(v0, v1);
}

// ---------------------------------------------------------------------------
// pos: 2 res-blocks over (B,128,2048); one wave per 32 columns. f32 out.
// ---------------------------------------------------------------------------
__global__ __launch_bounds__(256) void pos_kernel(const u16* __restrict__ x_mid,
    const u16* __restrict__ pos_w1, const u16* __restrict__ pos_w2,
    const float* __restrict__ bns, float* __restrict__ out_x){
  __shared__ __align__(16) u16 X[4][32*LDSPAD];
  const int wid = threadIdx.x >> 6, lane = threadIdx.x & 63;
  const int q = lane >> 4, l15 = lane & 15;
  const int g = blockIdx.x*4 + wid;            // 0..511
  const int gc0 = g * 32;
  const int b = gc0 >> 11, s0 = gc0 & 2047;
  u16* Xw = X[wid];
  #pragma unroll
  for (int it = 0; it < 8; ++it){
    int lidx = it*64 + lane;
    int col = lidx >> 4, kq = lidx & 15;
    uint4 v = *(const uint4*)(x_mid + (size_t)(gc0 + col)*COUT + kq*8);
    *(uint4*)(Xw + col*LDSPAD + kq*8) = v;
  }
  __syncthreads();
  u32 resid[8][2][2];
  #pragma unroll
  for (int mt = 0; mt < 8; ++mt)
    #pragma unroll
    for (int nt = 0; nt < 2; ++nt){
      uint2 rr = *(const uint2*)(Xw + (nt*16 + l15)*LDSPAD + mt*16 + q*4);
      resid[mt][nt][0] = rr.x; resid[mt][nt][1] = rr.y;
    }
  f32x4 acc[8][2];
  res_block(pos_w1,             pos_w2,             bns + 1280, bns + 1536, Xw, q, l15, resid, acc, true);
  res_block(pos_w1 + COUT*COUT, pos_w2 + COUT*COUT, bns + 1792, bns + 2048, Xw, q, l15, resid, acc, false);
  #pragma unroll
  for (int mt = 0; mt < 8; ++mt)
    #pragma unroll
    for (int nt = 0; nt < 2; ++nt)
      #pragma unroll
      for (int r = 0; r < 4; ++r){
        int row = mt*16 + q*4 + r;
        int colx = s0 + nt*16 + l15;
        out_x[(size_t)(b*COUT + row)*NS + colx] = acc[mt][nt][r];
      }
}

// ---------------------------------------------------------------------------
extern "C" void kernel_launch(void* const* d_in, const int* in_sizes, int n_in,
                              void* d_out, int out_size, void* d_ws, size_t ws_size,
                              hipStream_t stream){
  (void)in_sizes; (void)n_in; (void)out_size; (void)ws_size;
  const float* xyz    = (const float*)d_in[0];
  const float* feat   = (const float*)d_in[1];

  // ws layout (16B aligned, ~6.4 MB total):
  char* ws = (char*)d_ws;
  float* bns     = (float*)ws;                          // 16 KiB (9.2 used)
  u16*   wbf     = (u16*)(ws + 16384);                  // 288 KiB bf16 weights
  int*   fps_idx = (int*)(ws + 16384 + 294912);         // 64 KiB
  int*   knn     = (int*)(ws + 16384 + 294912 + 65536); // 2 MiB
  u16*   x_mid   = (u16*)(ws + 16384 + 294912 + 65536 + 2097152); // 4 MiB
  float* out_xyz = (float*)d_out;                       // (8,2048,3) f32
  float* out_x   = (float*)d_out + B_*NS*3;             // (8,128,2048) f32

  // bf16 weight staging: te(16384) pre_w1(32768) pre_w2(32768) pos_w1(32768) pos_w2(32768)
  u16* te_w   = wbf;
  u16* pre_w1 = wbf + 16384;
  u16* pre_w2 = wbf + 49152;
  u16* pos_w1 = wbf + 81920;
  u16* pos_w2 = wbf + 114688;
  wcvt_kernel<<<64,  256, 0, stream>>>((const float*)d_in[2],  te_w,   16384);
  wcvt_kernel<<<128, 256, 0, stream>>>((const float*)d_in[7],  pre_w1, 32768);
  wcvt_kernel<<<128, 256, 0, stream>>>((const float*)d_in[8],  pre_w2, 32768);
  wcvt_kernel<<<128, 256, 0, stream>>>((const float*)d_in[17], pos_w1, 32768);
  wcvt_kernel<<<128, 256, 0, stream>>>((const float*)d_in[18], pos_w2, 32768);

  // dict order: te_g/b/m/v = 3..6 ; pre: w1,w2,g1,g2,b1,b2,m1,m2,v1,v2 = 7..16 ; pos = 17..26
  BnPtrs bp;
  const int gi[9] = {3, 9, 10, 9, 10, 19, 20, 19, 20};
  const int bbi[9]= {4, 11,12, 11,12, 21, 22, 21, 22};
  const int mi[9] = {5, 13,14, 13,14, 23, 24, 23, 24};
  const int vi[9] = {6, 15,16, 15,16, 25, 26, 25, 26};
  const int of[9] = {0, 0, 0, 128,128, 0, 0, 128,128};
  for (int k = 0; k < 9; ++k){
    bp.g[k] = (const float*)d_in[gi[k]]  + of[k];
    bp.b[k] = (const float*)d_in[bbi[k]] + of[k];
    bp.m[k] = (const float*)d_in[mi[k]]  + of[k];
    bp.v[k] = (const float*)d_in[vi[k]]  + of[k];
  }

  bn_pre_kernel<<<9, 128, 0, stream>>>(bp, bns);
  fps_kernel<<<B_, 512, 0, stream>>>(xyz, fps_idx);
  knn_kernel<<<(B_*NS)/4, 256, 0, stream>>>(xyz, fps_idx, knn, out_xyz);
  mid_kernel<<<(B_*NS)/4, 256, 0, stream>>>(feat, te_w, pre_w1, pre_w2, bns, fps_idx, knn, x_mid);
  pos_kernel<<<(B_*NS/K_)/4, 256, 0, stream>>>(x_mid, pos_w1, pos_w2, bns, out_x);
}